// Round 10
// baseline (5763.190 us; speedup 1.0000x reference)
//
#include <hip/hip_runtime.h>
#include <math.h>

// RNN scan, SEQ=2048, BATCH=64, I=H=O=256, fp32.
// CHAOS (per-step gain ~2.5x): pass requires bit-exact replication of the
// golden pipeline. Model this round: golden = jax/XLA-CPU fp32:
//   dots : Eigen gebp -> per-element single-acc ascending-k FMA chain
//   +bh, +xp : one fadd each
//   tanh : XLA EmitTanh / Eigen generic_fast_tanh_float:
//          clamp +-7.99881172180175781 (NOT 9 -- round-8 bug),
//          FMA-contracted Horner (fast-math AllowFPOpFusion),
//          exact fdiv, |x|<4e-4 -> x (unclamped).
// Output GEMM (outside feedback loop): free-form fp32 (2% tolerance).
// WS-FREE: xp lives in d_out outputs region; scan overwrites xp[t] with h[t];
// phase 3 in-place h -> h@Vo + co.

#define SEQ 2048
#define BATCH 64
#define HID 256
#define BH 16384  // BATCH*HID

// Eigen/XLA fast-tanh f32, FMA evaluation, clamp 7.99881172180175781.
__device__ __forceinline__ float tanh_xla(float x) {
  const float kClamp = 7.99881172180175781f;
  float xc = fminf(fmaxf(x, -kClamp), kClamp);   // pmax(pmin(..)) order; no NaNs here
  float x2 = __fmul_rn(xc, xc);
  float p = __fmaf_rn(x2, -2.76076847742355e-16f, 2.00018790482477e-13f);
  p = __fmaf_rn(x2, p, -8.60467152213735e-11f);
  p = __fmaf_rn(x2, p, 5.12229709037114e-08f);
  p = __fmaf_rn(x2, p, 1.48572235717979e-05f);
  p = __fmaf_rn(x2, p, 6.37261928875436e-04f);
  p = __fmaf_rn(x2, p, 4.89352455891786e-03f);
  p = __fmul_rn(xc, p);
  float q = __fmaf_rn(x2, 1.19825839466702e-06f, 1.18534705686654e-04f);
  q = __fmaf_rn(x2, q, 2.26843463243900e-03f);
  q = __fmaf_rn(x2, q, 4.89352518554385e-03f);
  float r = __fdiv_rn(p, q);
  return (fabsf(x) < 0.0004f) ? x : r;
}

// ---------------------------------------------------------------------------
// K1: xp = X @ Ux + bh. Per element: single-acc ascending-i FMA chain
// (Eigen dot order), then one fadd for bias. Block = 8 rows; thread = col h.
// ---------------------------------------------------------------------------
__global__ __launch_bounds__(256) void xp_dot_kernel(
    const float* __restrict__ X, const float* __restrict__ Ux,
    const float* __restrict__ bh, float* __restrict__ XP) {
  __shared__ float xs[8][256];

  const int tid = threadIdx.x;
  const size_t row0 = (size_t)blockIdx.x * 8;

  const float4* src = (const float4*)(X + row0 * 256);
  float4* dst = (float4*)&xs[0][0];
  dst[tid] = src[tid];
  dst[256 + tid] = src[256 + tid];
  __syncthreads();

  const int h = tid;
  float acc[8] = {0.f, 0.f, 0.f, 0.f, 0.f, 0.f, 0.f, 0.f};

#pragma unroll 4
  for (int i = 0; i < 256; ++i) {
    float u = Ux[i * 256 + h];
#pragma unroll
    for (int r = 0; r < 8; ++r)
      acc[r] = __fmaf_rn(xs[r][i], u, acc[r]);   // ascending i, single acc
  }

  const float b = bh[h];
#pragma unroll
  for (int r = 0; r < 8; ++r)
    XP[(row0 + r) * 256 + h] = __fadd_rn(acc[r], b);
}

// ---------------------------------------------------------------------------
// K2: scan. One block per batch row; thread j owns column j, holds Wh[:,j]
// (256 floats) in VGPRs. Per step: acc = ascending-k FMA chain over h_lds
// (Eigen sgemm order); z = fadd(xp, acc); h' = tanh_xla(z).
// ---------------------------------------------------------------------------
__global__ __launch_bounds__(256, 1) void scan_xla_kernel(
    const float* __restrict__ Wh, const float* __restrict__ h0,
    float* __restrict__ xpH, float* __restrict__ hfinal) {
  __shared__ float h_lds[256];

  const int b = blockIdx.x;
  const int j = threadIdx.x;

  float w[256];
#pragma unroll
  for (int k = 0; k < 256; ++k) w[k] = Wh[k * 256 + j];  // column j

  h_lds[j] = h0[b * 256 + j];
  __syncthreads();

  float xp_cur = xpH[(size_t)b * 256 + j];  // xp[t=0]

  for (int t = 0; t < SEQ; ++t) {
    float xp_next = (t + 1 < SEQ) ? xpH[(size_t)(t + 1) * BH + b * 256 + j] : 0.f;

    float acc = 0.f;
#pragma unroll
    for (int k = 0; k < 256; ++k)
      acc = __fmaf_rn(h_lds[k], w[k], acc);   // single acc, ascending k

    float z = __fadd_rn(xp_cur, acc);
    float hn = tanh_xla(z);

    __syncthreads();                           // all h_lds reads done
    h_lds[j] = hn;
    xpH[(size_t)t * BH + b * 256 + j] = hn;    // overwrite xp slot with h_t
    __syncthreads();                           // h visible for next step

    xp_cur = xp_next;
  }

  hfinal[b * 256 + j] = h_lds[j];
}

// ---------------------------------------------------------------------------
// K3: in-place fp32 GEMM: rows of HO (M x 256) -> row @ Vo + co.
// Outside the feedback loop => rounding free. Block stages its own 64 rows
// in LDS then overwrites exactly those rows (race-free).
// ---------------------------------------------------------------------------
__global__ __launch_bounds__(256) void gemm_inplace_kernel(
    float* __restrict__ HO, const float* __restrict__ Vo,
    const float* __restrict__ co) {
  __shared__ float Hs[64][260];
  __shared__ float Bs[32][64];

  const int tid = threadIdx.x;
  const int bm = blockIdx.x;
  float* base = HO + (size_t)bm * 64 * 256;

#pragma unroll
  for (int l = 0; l < 16; ++l) {
    int idx = l * 256 + tid;
    int r = idx >> 6;
    int c4 = idx & 63;
    float4 v = *(const float4*)&base[r * 256 + c4 * 4];
    *(float4*)&Hs[r][c4 * 4] = v;
  }

  const int tr = tid >> 4;
  const int tc = tid & 15;

  for (int bn = 0; bn < 4; ++bn) {
    float acc[4][4];
#pragma unroll
    for (int i = 0; i < 4; ++i)
#pragma unroll
      for (int j = 0; j < 4; ++j) acc[i][j] = 0.f;

    for (int kt = 0; kt < 256; kt += 32) {
      __syncthreads();
#pragma unroll
      for (int l = 0; l < 2; ++l) {
        int idx = tid * 2 + l;
        int k2 = idx >> 4;
        int nn = (idx & 15) << 2;
        float4 bv = *(const float4*)&Vo[(size_t)(kt + k2) * 256 + bn * 64 + nn];
        *(float4*)&Bs[k2][nn] = bv;
      }
      __syncthreads();
#pragma unroll
      for (int k = 0; k < 32; ++k) {
        float4 bq = *(const float4*)&Bs[k][tc * 4];
        float bv[4] = {bq.x, bq.y, bq.z, bq.w};
#pragma unroll
        for (int i = 0; i < 4; ++i) {
          float a = Hs[tr * 4 + i][kt + k];
#pragma unroll
          for (int j = 0; j < 4; ++j) acc[i][j] += a * bv[j];
        }
      }
    }

    const float4 cb = *(const float4*)&co[bn * 64 + tc * 4];
    const float cv[4] = {cb.x, cb.y, cb.z, cb.w};
#pragma unroll
    for (int i = 0; i < 4; ++i) {
      float4 o;
      o.x = acc[i][0] + cv[0];
      o.y = acc[i][1] + cv[1];
      o.z = acc[i][2] + cv[2];
      o.w = acc[i][3] + cv[3];
      *(float4*)&base[(tr * 4 + i) * 256 + bn * 64 + tc * 4] = o;
    }
  }
}

extern "C" void kernel_launch(void* const* d_in, const int* in_sizes, int n_in,
                              void* d_out, int out_size, void* d_ws, size_t ws_size,
                              hipStream_t stream) {
  const float* inputs = (const float*)d_in[0];
  const float* h0     = (const float*)d_in[1];
  const float* Wh     = (const float*)d_in[2];
  const float* Ux     = (const float*)d_in[3];
  const float* bh     = (const float*)d_in[4];
  const float* Vo     = (const float*)d_in[5];
  const float* co     = (const float*)d_in[6];

  float* out = (float*)d_out;                       // outputs (S,B,O)
  float* hfinal = out + (size_t)SEQ * BATCH * 256;  // ht_final (B,H)
  (void)d_ws; (void)ws_size;

  const int M = SEQ * BATCH;  // 131072 rows

  // K1: xp (Eigen-order FMA chain + bias add) -> d_out outputs region
  xp_dot_kernel<<<M / 8, 256, 0, stream>>>(inputs, Ux, bh, out);

  // K2: XLA-exact scan (clamp 7.99881, FMA tanh); overwrites xp[t] with h[t].
  scan_xla_kernel<<<BATCH, 256, 0, stream>>>(Wh, h0, out, hfinal);

  // K3: in-place outputs = H @ Vo + co.
  gemm_inplace_kernel<<<M / 64, 256, 0, stream>>>(out, Vo, co);
}